// Round 2
// baseline (19199.748 us; speedup 1.0000x reference)
//
#include <hip/hip_runtime.h>
#include <hip/hip_bf16.h>

#define BATCH   2
#define FRAMES  8
#define GRID_   14
#define NTOK    196
#define PS      16
#define IMG     224
#define L_SEQ   1568
#define DM      384
#define DI      768
#define DTR     24
#define DS      16
#define DEPTH   24
#define KCONV   4
#define NROWS   (BATCH*L_SEQ)   // 3136
#define EPS_    1e-5f

// ---------------- patchify: x (B,3,T,224,224) f32 -> patches (3136, 768) f32 ----
__global__ __launch_bounds__(256) void patchify_kernel(const float* __restrict__ x,
                                                       float* __restrict__ patches){
    int idx = blockIdx.x*256 + threadIdx.x;
    if (idx >= NROWS*768) return;
    int k   = idx % 768;
    int r   = idx / 768;          // (b*8+t)*196 + tok
    int tok = r % NTOK;
    int bt  = r / NTOK;
    int t = bt % FRAMES, b = bt / FRAMES;
    int gy = tok / GRID_, gx = tok % GRID_;
    int c = k / 256; int rem = k % 256; int py = rem/16, px = rem%16;
    long xo = (((long)(b*3 + c)*FRAMES + t)*IMG + (gy*PS+py))*IMG + (gx*PS+px);
    patches[idx] = x[xo];
}

// ---------------- generic tiled GEMM: C[M,N] = A[M,K(lda)] * W[N,K]^T ------------
// modes: 0 plain f32 out (ld=N); 1 in_proj split xi/zi; 2 patch epilogue; 3 softplus(dt)+bias
__global__ __launch_bounds__(256) void gemm_kernel(
        const float* __restrict__ A, const float* __restrict__ A2, int lda,
        const float* __restrict__ W, int K, int N,
        float* __restrict__ out0, float* __restrict__ out1, int mode,
        const float* __restrict__ aux0, const float* __restrict__ aux1,
        const float* __restrict__ aux2)
{
    __shared__ float As[16][64];
    __shared__ float Bs[16][64];
    int tid = threadIdx.x;
    int tx = tid & 15, ty = tid >> 4;
    int m0 = blockIdx.y * 64, n0 = blockIdx.x * 64;
    int lrow = tid >> 2, lq = tid & 3;
    float acc[4][4] = {};

    for (int k0 = 0; k0 < K; k0 += 16){
        float4 av = {0.f,0.f,0.f,0.f};
        if (k0 + lq*4 < K){
            const float* ap = A + (long)(m0+lrow)*lda + k0 + lq*4;
            av = *(const float4*)ap;
            if (A2){
                const float* ap2 = A2 + (long)(m0+lrow)*lda + k0 + lq*4;
                float4 a2 = *(const float4*)ap2;
                av.x += a2.x; av.y += a2.y; av.z += a2.z; av.w += a2.w;
            }
        }
        float4 wv = {0.f,0.f,0.f,0.f};
        if ((n0 + lrow) < N && (k0 + lq*4) < K){
            const float* wp = W + (long)(n0+lrow)*K + k0 + lq*4;
            wv = *(const float4*)wp;
        }
        As[lq*4+0][lrow] = av.x; As[lq*4+1][lrow] = av.y;
        As[lq*4+2][lrow] = av.z; As[lq*4+3][lrow] = av.w;
        Bs[lq*4+0][lrow] = wv.x; Bs[lq*4+1][lrow] = wv.y;
        Bs[lq*4+2][lrow] = wv.z; Bs[lq*4+3][lrow] = wv.w;
        __syncthreads();
        #pragma unroll
        for (int kk = 0; kk < 16; kk++){
            float4 a = *(float4*)&As[kk][ty*4];
            float4 b = *(float4*)&Bs[kk][tx*4];
            acc[0][0] += a.x*b.x; acc[0][1] += a.x*b.y; acc[0][2] += a.x*b.z; acc[0][3] += a.x*b.w;
            acc[1][0] += a.y*b.x; acc[1][1] += a.y*b.y; acc[1][2] += a.y*b.z; acc[1][3] += a.y*b.w;
            acc[2][0] += a.z*b.x; acc[2][1] += a.z*b.y; acc[2][2] += a.z*b.z; acc[2][3] += a.z*b.w;
            acc[3][0] += a.w*b.x; acc[3][1] += a.w*b.y; acc[3][2] += a.w*b.z; acc[3][3] += a.w*b.w;
        }
        __syncthreads();
    }

    #pragma unroll
    for (int i = 0; i < 4; i++){
        int r = m0 + ty*4 + i;
        #pragma unroll
        for (int j = 0; j < 4; j++){
            int cn = n0 + tx*4 + j;
            float v = acc[i][j];
            if (mode == 1){
                if (cn < DI) out0[(long)r*DI + cn] = v;
                else         out1[(long)r*DI + cn - DI] = v;
            } else if (cn < N){
                if (mode == 0){
                    out0[(long)r*N + cn] = v;
                } else if (mode == 2){
                    int tok = r % NTOK, t = (r/NTOK) % FRAMES;
                    out0[(long)r*N + cn] = v + aux0[cn] + aux1[tok*DM+cn] + aux2[t*DM+cn];
                } else { // mode 3: softplus + bias
                    float xs = v + aux0[cn];
                    out0[(long)r*N + cn] = (xs > 20.f) ? xs : log1pf(__expf(xs));
                }
            }
        }
    }
}

// ---------------- rmsnorm (+ residual add) ---------------------------------------
__global__ __launch_bounds__(128) void rmsnorm_kernel(
        float* __restrict__ res, const float* __restrict__ h,
        float* __restrict__ outf, const float* __restrict__ w)
{
    int r = blockIdx.x; int tid = threadIdx.x;
    const float* hr = h + (long)r*DM;
    float* rr = res + (long)r*DM;
    float v[3]; float ss = 0.f;
    #pragma unroll
    for (int i = 0; i < 3; i++){
        int c = tid + i*128;
        float x = rr[c] + hr[c];
        rr[c] = x; v[i] = x; ss += x*x;
    }
    #pragma unroll
    for (int off = 32; off; off >>= 1) ss += __shfl_down(ss, off, 64);
    __shared__ float wsum[2];
    if ((tid & 63) == 0) wsum[tid >> 6] = ss;
    __syncthreads();
    float scale = rsqrtf((wsum[0] + wsum[1]) / (float)DM + EPS_);
    #pragma unroll
    for (int i = 0; i < 3; i++){
        int c = tid + i*128;
        outf[(long)r*DM + c] = v[i] * scale * w[c];
    }
}

// ---------------- depthwise causal conv + silu, both directions ------------------
__global__ __launch_bounds__(256) void conv_kernel(
        const float* __restrict__ xi,
        const float* __restrict__ cw_f, const float* __restrict__ cb_f,
        const float* __restrict__ cw_b, const float* __restrict__ cb_b,
        float* __restrict__ xc)
{
    int idx = blockIdx.x*256 + threadIdx.x;
    if (idx >= 2*NROWS*768) return;
    int d  = idx % 768;
    int r2 = idx / 768;             // dir*NROWS + b*L + p
    int dir = r2 / NROWS;
    int rr  = r2 % NROWS;
    int b = rr / L_SEQ, p = rr % L_SEQ;
    const float* cw = dir ? cw_b : cw_f;
    const float* cb = dir ? cb_b : cb_f;
    float acc = cb[d];
    #pragma unroll
    for (int j = 0; j < KCONV; j++){
        int pp = p - (KCONV-1) + j;
        if (pp >= 0){
            int phys = dir ? (L_SEQ-1-pp) : pp;
            acc += cw[d*KCONV+j] * xi[((long)b*L_SEQ + phys)*DI + d];
        }
    }
    float sg = 1.f/(1.f + __expf(-acc));
    xc[idx] = acc * sg;
}

// ---------------- selective scan, thread per (b,d,n), both directions ------------
__global__ __launch_bounds__(256) void scan_kernel(
        const float* __restrict__ xc2, const float* __restrict__ dt2,
        const float* __restrict__ xdbl2, const float* __restrict__ zi,
        const float* __restrict__ Alog_f, const float* __restrict__ Dp_f,
        const float* __restrict__ Alog_b, const float* __restrict__ Dp_b,
        float* __restrict__ ys_f, float* __restrict__ ys_b)
{
    int dchunk = blockIdx.x;        // 48 chunks of 16 d
    int b   = blockIdx.y;
    int dir = blockIdx.z;
    int tid = threadIdx.x;
    int n = tid & 15, dg = tid >> 4;
    int dbase = dchunk*16;
    int d = dbase + dg;

    const float* xc = xc2 + (long)dir*NROWS*DI;
    const float* dt = dt2 + (long)dir*NROWS*DI;
    const float* xd = xdbl2 + (long)dir*NROWS*56;
    const float* Alog = dir ? Alog_b : Alog_f;
    const float* Dpp  = dir ? Dp_b   : Dp_f;
    float* ys = dir ? ys_b : ys_f;

    float Aval = -__expf(Alog[d*DS + n]);
    float Dval = Dpp[d];

    __shared__ float sdt[64][16], sxc[64][16], sB[64][16], sC[64][16], sz[64][16];
    float h = 0.f;

    for (int c0 = 0; c0 < L_SEQ; c0 += 64){
        int CL = min(64, L_SEQ - c0);
        __syncthreads();
        for (int e = tid; e < CL*16; e += 256){
            int s = e >> 4, q = e & 15;
            int p = c0 + s;
            int phys = dir ? (L_SEQ-1-p) : p;
            long row  = (long)b*L_SEQ + p;
            long prow = (long)b*L_SEQ + phys;
            sdt[s][q] = dt[row*DI + dbase + q];
            sxc[s][q] = xc[row*DI + dbase + q];
            sB[s][q]  = xd[row*56 + DTR + q];
            sC[s][q]  = xd[row*56 + DTR + DS + q];
            sz[s][q]  = zi[prow*DI + dbase + q];
        }
        __syncthreads();
        for (int s = 0; s < CL; s++){
            float dtv = sdt[s][dg], xcv = sxc[s][dg];
            float dA = __expf(dtv * Aval);
            h = dA*h + dtv*xcv*sB[s][n];
            float contrib = h * sC[s][n];
            contrib += __shfl_xor(contrib, 8, 16);
            contrib += __shfl_xor(contrib, 4, 16);
            contrib += __shfl_xor(contrib, 2, 16);
            contrib += __shfl_xor(contrib, 1, 16);
            if (n == 0){
                int p = c0 + s;
                int phys = dir ? (L_SEQ-1-p) : p;
                long orow = (long)b*L_SEQ + phys;
                float zv = sz[s][dg];
                float sg = 1.f/(1.f + __expf(-zv));
                ys[orow*DI + d] = (contrib + Dval*xcv) * (zv*sg);
            }
        }
    }
}

// ---------------- final rmsnorm: (res+h) normalized, f32 out ---------------------
__global__ __launch_bounds__(128) void rmsnorm_final_kernel(
        const float* __restrict__ res, const float* __restrict__ h,
        const float* __restrict__ w, float* __restrict__ out)
{
    int r = blockIdx.x; int tid = threadIdx.x;
    const float* hr = h + (long)r*DM;
    const float* rr = res + (long)r*DM;
    float v[3]; float ss = 0.f;
    #pragma unroll
    for (int i = 0; i < 3; i++){
        int c = tid + i*128;
        float x = rr[c] + hr[c];
        v[i] = x; ss += x*x;
    }
    #pragma unroll
    for (int off = 32; off; off >>= 1) ss += __shfl_down(ss, off, 64);
    __shared__ float wsum[2];
    if ((tid & 63) == 0) wsum[tid >> 6] = ss;
    __syncthreads();
    float scale = rsqrtf((wsum[0] + wsum[1]) / (float)DM + EPS_);
    #pragma unroll
    for (int i = 0; i < 3; i++){
        int c = tid + i*128;
        out[(long)r*DM + c] = v[i] * scale * w[c];
    }
}

extern "C" void kernel_launch(void* const* d_in, const int* in_sizes, int n_in,
                              void* d_out, int out_size, void* d_ws, size_t ws_size,
                              hipStream_t stream)
{
    const float* x         = (const float*)d_in[0];
    const float* patch_w   = (const float*)d_in[1];
    const float* patch_b   = (const float*)d_in[2];
    const float* pos_embed = (const float*)d_in[3];
    const float* temp_pos  = (const float*)d_in[4];
    const float* in_proj   = (const float*)d_in[5];
    const float* conv_w    = (const float*)d_in[6];
    const float* conv_b    = (const float*)d_in[7];
    const float* xproj_w   = (const float*)d_in[8];
    const float* dt_w      = (const float*)d_in[9];
    const float* dt_b      = (const float*)d_in[10];
    const float* A_log     = (const float*)d_in[11];
    const float* Dp        = (const float*)d_in[12];
    const float* conv_w_b  = (const float*)d_in[13];
    const float* conv_b_b  = (const float*)d_in[14];
    const float* xproj_w_b = (const float*)d_in[15];
    const float* dt_w_b    = (const float*)d_in[16];
    const float* dt_b_b    = (const float*)d_in[17];
    const float* A_log_b   = (const float*)d_in[18];
    const float* Dp_b      = (const float*)d_in[19];
    const float* out_proj  = (const float*)d_in[20];
    const float* norm_w    = (const float*)d_in[21];
    const float* norm_f    = (const float*)d_in[22];

    float* ws = (float*)d_ws;
    size_t off = 0;
    float* patches  = ws + off; off += (size_t)NROWS*768;      // 2,408,448
    float* hidden   = ws + off; off += (size_t)NROWS*DM;       // 1,204,224
    float* residual = ws + off; off += (size_t)NROWS*DM;
    float* hnorm    = ws + off; off += (size_t)NROWS*DM;
    float* xi       = ws + off; off += (size_t)NROWS*DI;
    float* ziB      = ws + off; off += (size_t)NROWS*DI;
    float* xc2      = ws + off; off += (size_t)2*NROWS*DI;
    float* xdbl2    = ws + off; off += (size_t)2*NROWS*56;
    float* dt2      = ws + off; off += (size_t)2*NROWS*DI;
    float* ysb      = ws + off; off += (size_t)NROWS*DI;
    float* ysf      = patches;  // alias: patches dead after patch GEMM

    hipMemsetAsync(residual, 0, (size_t)NROWS*DM*sizeof(float), stream);

    patchify_kernel<<<(NROWS*768+255)/256, 256, 0, stream>>>(x, patches);
    // patch embed: (3136,768)x(384,768)^T + bias + pos + temp -> hidden
    gemm_kernel<<<dim3(DM/64, NROWS/64), 256, 0, stream>>>(
        patches, nullptr, 768, patch_w, 768, DM, hidden, nullptr, 2,
        patch_b, pos_embed, temp_pos);

    for (int l = 0; l < DEPTH; l++){
        rmsnorm_kernel<<<NROWS, 128, 0, stream>>>(residual, hidden, hnorm,
                                                  norm_w + (size_t)l*DM);
        // in_proj: (3136,384)x(1536,384)^T -> xi, zi
        gemm_kernel<<<dim3(2*DI/64, NROWS/64), 256, 0, stream>>>(
            hnorm, nullptr, DM, in_proj + (size_t)l*2*DI*DM, DM, 2*DI,
            xi, ziB, 1, nullptr, nullptr, nullptr);
        // conv both dirs
        conv_kernel<<<(2*NROWS*768+255)/256, 256, 0, stream>>>(
            xi, conv_w + (size_t)l*DI*KCONV, conv_b + (size_t)l*DI,
            conv_w_b + (size_t)l*DI*KCONV, conv_b_b + (size_t)l*DI, xc2);
        // xproj fwd / bwd: (3136,768)x(56,768)^T -> xdbl
        gemm_kernel<<<dim3(1, NROWS/64), 256, 0, stream>>>(
            xc2, nullptr, DI, xproj_w + (size_t)l*56*DI, DI, 56,
            xdbl2, nullptr, 0, nullptr, nullptr, nullptr);
        gemm_kernel<<<dim3(1, NROWS/64), 256, 0, stream>>>(
            xc2 + (size_t)NROWS*DI, nullptr, DI, xproj_w_b + (size_t)l*56*DI, DI, 56,
            xdbl2 + (size_t)NROWS*56, nullptr, 0, nullptr, nullptr, nullptr);
        // dt: (3136,first 24 of 56)x(768,24)^T + bias, softplus
        gemm_kernel<<<dim3(DI/64, NROWS/64), 256, 0, stream>>>(
            xdbl2, nullptr, 56, dt_w + (size_t)l*DI*DTR, DTR, DI,
            dt2, nullptr, 3, dt_b + (size_t)l*DI, nullptr, nullptr);
        gemm_kernel<<<dim3(DI/64, NROWS/64), 256, 0, stream>>>(
            xdbl2 + (size_t)NROWS*56, nullptr, 56, dt_w_b + (size_t)l*DI*DTR, DTR, DI,
            dt2 + (size_t)NROWS*DI, nullptr, 3, dt_b_b + (size_t)l*DI, nullptr, nullptr);
        // scan, both dirs in one dispatch
        scan_kernel<<<dim3(DI/16, BATCH, 2), 256, 0, stream>>>(
            xc2, dt2, xdbl2, ziB,
            A_log + (size_t)l*DI*DS, Dp + (size_t)l*DI,
            A_log_b + (size_t)l*DI*DS, Dp_b + (size_t)l*DI, ysf, ysb);
        // out_proj: (yf+yb)(3136,768) x (384,768)^T -> hidden
        gemm_kernel<<<dim3(DM/64, NROWS/64), 256, 0, stream>>>(
            ysf, ysb, DI, out_proj + (size_t)l*DM*DI, DI, DM,
            hidden, nullptr, 0, nullptr, nullptr, nullptr);
    }

    rmsnorm_final_kernel<<<NROWS, 128, 0, stream>>>(residual, hidden,
                                                    norm_f, (float*)d_out);
}

// Round 3
// 9727.068 us; speedup vs baseline: 1.9738x; 1.9738x over previous
//
#include <hip/hip_runtime.h>
#include <hip/hip_bf16.h>

#define BATCH   2
#define FRAMES  8
#define GRID_   14
#define NTOK    196
#define PS      16
#define IMG     224
#define L_SEQ   1568
#define DM      384
#define DI      768
#define DTR     24
#define DS      16
#define DEPTH   24
#define KCONV   4
#define NROWS   (BATCH*L_SEQ)   // 3136
#define EPS_    1e-5f
#define NCHUNK  32
#define CLEN    49              // 32*49 = 1568

// ---------------- patchify: x (B,3,T,224,224) f32 -> patches (3136, 768) f32 ----
__global__ __launch_bounds__(256) void patchify_kernel(const float* __restrict__ x,
                                                       float* __restrict__ patches){
    int idx = blockIdx.x*256 + threadIdx.x;
    if (idx >= NROWS*768) return;
    int k   = idx % 768;
    int r   = idx / 768;          // (b*8+t)*196 + tok
    int tok = r % NTOK;
    int bt  = r / NTOK;
    int t = bt % FRAMES, b = bt / FRAMES;
    int gy = tok / GRID_, gx = tok % GRID_;
    int c = k / 256; int rem = k % 256; int py = rem/16, px = rem%16;
    long xo = (((long)(b*3 + c)*FRAMES + t)*IMG + (gy*PS+py))*IMG + (gx*PS+px);
    patches[idx] = x[xo];
}

// ---------------- generic tiled GEMM: C[M,N] = A[M,K(lda)] * W[N,K]^T ------------
// modes: 0 plain f32 out (ld=N); 1 in_proj split xi/zi; 2 patch epilogue; 3 softplus(dt)+bias
__global__ __launch_bounds__(256) void gemm_kernel(
        const float* __restrict__ A, const float* __restrict__ A2, int lda,
        const float* __restrict__ W, int K, int N,
        float* __restrict__ out0, float* __restrict__ out1, int mode,
        const float* __restrict__ aux0, const float* __restrict__ aux1,
        const float* __restrict__ aux2)
{
    __shared__ float As[16][64];
    __shared__ float Bs[16][64];
    int tid = threadIdx.x;
    int tx = tid & 15, ty = tid >> 4;
    int m0 = blockIdx.y * 64, n0 = blockIdx.x * 64;
    int lrow = tid >> 2, lq = tid & 3;
    float acc[4][4] = {};

    for (int k0 = 0; k0 < K; k0 += 16){
        float4 av = {0.f,0.f,0.f,0.f};
        if (k0 + lq*4 < K){
            const float* ap = A + (long)(m0+lrow)*lda + k0 + lq*4;
            av = *(const float4*)ap;
            if (A2){
                const float* ap2 = A2 + (long)(m0+lrow)*lda + k0 + lq*4;
                float4 a2 = *(const float4*)ap2;
                av.x += a2.x; av.y += a2.y; av.z += a2.z; av.w += a2.w;
            }
        }
        float4 wv = {0.f,0.f,0.f,0.f};
        if ((n0 + lrow) < N && (k0 + lq*4) < K){
            const float* wp = W + (long)(n0+lrow)*K + k0 + lq*4;
            wv = *(const float4*)wp;
        }
        As[lq*4+0][lrow] = av.x; As[lq*4+1][lrow] = av.y;
        As[lq*4+2][lrow] = av.z; As[lq*4+3][lrow] = av.w;
        Bs[lq*4+0][lrow] = wv.x; Bs[lq*4+1][lrow] = wv.y;
        Bs[lq*4+2][lrow] = wv.z; Bs[lq*4+3][lrow] = wv.w;
        __syncthreads();
        #pragma unroll
        for (int kk = 0; kk < 16; kk++){
            float4 a = *(float4*)&As[kk][ty*4];
            float4 b = *(float4*)&Bs[kk][tx*4];
            acc[0][0] += a.x*b.x; acc[0][1] += a.x*b.y; acc[0][2] += a.x*b.z; acc[0][3] += a.x*b.w;
            acc[1][0] += a.y*b.x; acc[1][1] += a.y*b.y; acc[1][2] += a.y*b.z; acc[1][3] += a.y*b.w;
            acc[2][0] += a.z*b.x; acc[2][1] += a.z*b.y; acc[2][2] += a.z*b.z; acc[2][3] += a.z*b.w;
            acc[3][0] += a.w*b.x; acc[3][1] += a.w*b.y; acc[3][2] += a.w*b.z; acc[3][3] += a.w*b.w;
        }
        __syncthreads();
    }

    #pragma unroll
    for (int i = 0; i < 4; i++){
        int r = m0 + ty*4 + i;
        #pragma unroll
        for (int j = 0; j < 4; j++){
            int cn = n0 + tx*4 + j;
            float v = acc[i][j];
            if (mode == 1){
                if (cn < DI) out0[(long)r*DI + cn] = v;
                else         out1[(long)r*DI + cn - DI] = v;
            } else if (cn < N){
                if (mode == 0){
                    out0[(long)r*N + cn] = v;
                } else if (mode == 2){
                    int tok = r % NTOK, t = (r/NTOK) % FRAMES;
                    out0[(long)r*N + cn] = v + aux0[cn] + aux1[tok*DM+cn] + aux2[t*DM+cn];
                } else { // mode 3: softplus + bias
                    float xs = v + aux0[cn];
                    out0[(long)r*N + cn] = (xs > 20.f) ? xs : log1pf(__expf(xs));
                }
            }
        }
    }
}

// ---------------- rmsnorm (+ residual add) ---------------------------------------
__global__ __launch_bounds__(128) void rmsnorm_kernel(
        float* __restrict__ res, const float* __restrict__ h,
        float* __restrict__ outf, const float* __restrict__ w)
{
    int r = blockIdx.x; int tid = threadIdx.x;
    const float* hr = h + (long)r*DM;
    float* rr = res + (long)r*DM;
    float v[3]; float ss = 0.f;
    #pragma unroll
    for (int i = 0; i < 3; i++){
        int c = tid + i*128;
        float x = rr[c] + hr[c];
        rr[c] = x; v[i] = x; ss += x*x;
    }
    #pragma unroll
    for (int off = 32; off; off >>= 1) ss += __shfl_down(ss, off, 64);
    __shared__ float wsum[2];
    if ((tid & 63) == 0) wsum[tid >> 6] = ss;
    __syncthreads();
    float scale = rsqrtf((wsum[0] + wsum[1]) / (float)DM + EPS_);
    #pragma unroll
    for (int i = 0; i < 3; i++){
        int c = tid + i*128;
        outf[(long)r*DM + c] = v[i] * scale * w[c];
    }
}

// ---------------- depthwise causal conv + silu, both directions ------------------
__global__ __launch_bounds__(256) void conv_kernel(
        const float* __restrict__ xi,
        const float* __restrict__ cw_f, const float* __restrict__ cb_f,
        const float* __restrict__ cw_b, const float* __restrict__ cb_b,
        float* __restrict__ xc)
{
    int idx = blockIdx.x*256 + threadIdx.x;
    if (idx >= 2*NROWS*768) return;
    int d  = idx % 768;
    int r2 = idx / 768;             // dir*NROWS + b*L + p
    int dir = r2 / NROWS;
    int rr  = r2 % NROWS;
    int b = rr / L_SEQ, p = rr % L_SEQ;
    const float* cw = dir ? cw_b : cw_f;
    const float* cb = dir ? cb_b : cb_f;
    float acc = cb[d];
    #pragma unroll
    for (int j = 0; j < KCONV; j++){
        int pp = p - (KCONV-1) + j;
        if (pp >= 0){
            int phys = dir ? (L_SEQ-1-pp) : pp;
            acc += cw[d*KCONV+j] * xi[((long)b*L_SEQ + phys)*DI + d];
        }
    }
    float sg = 1.f/(1.f + __expf(-acc));
    xc[idx] = acc * sg;
}

// ---------------- chunked selective scan -----------------------------------------
// pass1: per chunk, local scan h from 0 -> S; cumulative decay P = exp(A*sum dt)
__global__ __launch_bounds__(256) void scan_pass1_kernel(
        const float* __restrict__ xc2, const float* __restrict__ dt2,
        const float* __restrict__ xdbl2,
        const float* __restrict__ Alog_f, const float* __restrict__ Alog_b,
        float* __restrict__ Pbuf, float* __restrict__ Sbuf)
{
    int dchunk = blockIdx.x;        // 48 tiles of 16 d
    int chunk  = blockIdx.y;        // 32 L-chunks
    int z      = blockIdx.z;        // b + 2*dir
    int b = z & 1, dir = z >> 1;
    int tid = threadIdx.x;
    int n = tid & 15, dg = tid >> 4;
    int dbase = dchunk*16;
    int d = dbase + dg;

    const float* xc = xc2 + (long)dir*NROWS*DI;
    const float* dt = dt2 + (long)dir*NROWS*DI;
    const float* xd = xdbl2 + (long)dir*NROWS*56;
    const float* Alog = dir ? Alog_b : Alog_f;
    float Aval = -__expf(Alog[d*DS + n]);

    __shared__ float sdt[CLEN][16], sxc[CLEN][16], sB[CLEN][16];
    int c0 = chunk * CLEN;
    for (int e = tid; e < CLEN*16; e += 256){
        int s = e >> 4, q = e & 15;
        long row = (long)b*L_SEQ + c0 + s;
        sdt[s][q] = dt[row*DI + dbase + q];
        sxc[s][q] = xc[row*DI + dbase + q];
        sB[s][q]  = xd[row*56 + DTR + q];
    }
    __syncthreads();

    float h = 0.f, dts = 0.f;
    for (int s = 0; s < CLEN; s++){
        float dtv = sdt[s][dg], xcv = sxc[s][dg];
        dts += dtv;
        h = __expf(dtv*Aval)*h + (dtv*xcv)*sB[s][n];
    }
    long idx = (((long)z*NCHUNK + chunk)*DI + d)*DS + n;
    Pbuf[idx] = __expf(Aval*dts);
    Sbuf[idx] = h;
}

// combine: per (z,d,n) lane, 32-step scan over chunks; Sbuf becomes Hin in place
__global__ __launch_bounds__(256) void scan_combine_kernel(
        const float* __restrict__ Pbuf, float* __restrict__ Sbuf)
{
    int gid = blockIdx.x*256 + threadIdx.x;     // over 4*DI*DS = 49152
    if (gid >= 4*DI*DS) return;
    int dn = gid % (DI*DS);
    int z  = gid / (DI*DS);
    long idx = (long)z*NCHUNK*DI*DS + dn;
    float Pv = Pbuf[idx], Sv = Sbuf[idx];
    float hin = 0.f;
    for (int c = 0; c < NCHUNK; c++){
        float Pn = 0.f, Sn = 0.f;
        if (c+1 < NCHUNK){ Pn = Pbuf[idx + DI*DS]; Sn = Sbuf[idx + DI*DS]; }
        Sbuf[idx] = hin;                        // Hin for chunk c
        hin = Pv*hin + Sv;
        Pv = Pn; Sv = Sn;
        idx += DI*DS;
    }
}

// pass2: redo local scan from Hin, emit y = C.h + D*xc, gated by silu(z)
__global__ __launch_bounds__(256) void scan_pass2_kernel(
        const float* __restrict__ xc2, const float* __restrict__ dt2,
        const float* __restrict__ xdbl2, const float* __restrict__ zi,
        const float* __restrict__ Alog_f, const float* __restrict__ Dp_f,
        const float* __restrict__ Alog_b, const float* __restrict__ Dp_b,
        const float* __restrict__ Hbuf,
        float* __restrict__ ys_f, float* __restrict__ ys_b)
{
    int dchunk = blockIdx.x;
    int chunk  = blockIdx.y;
    int z      = blockIdx.z;
    int b = z & 1, dir = z >> 1;
    int tid = threadIdx.x;
    int n = tid & 15, dg = tid >> 4;
    int dbase = dchunk*16;
    int d = dbase + dg;

    const float* xc = xc2 + (long)dir*NROWS*DI;
    const float* dt = dt2 + (long)dir*NROWS*DI;
    const float* xd = xdbl2 + (long)dir*NROWS*56;
    const float* Alog = dir ? Alog_b : Alog_f;
    const float* Dpp  = dir ? Dp_b   : Dp_f;
    float* ys = dir ? ys_b : ys_f;

    float Aval = -__expf(Alog[d*DS + n]);
    float Dval = Dpp[d];

    __shared__ float sdt[CLEN][16], sxc[CLEN][16], sB[CLEN][16], sC[CLEN][16], sz[CLEN][16];
    int c0 = chunk * CLEN;
    for (int e = tid; e < CLEN*16; e += 256){
        int s = e >> 4, q = e & 15;
        int p = c0 + s;
        int phys = dir ? (L_SEQ-1-p) : p;
        long row  = (long)b*L_SEQ + p;
        long prow = (long)b*L_SEQ + phys;
        sdt[s][q] = dt[row*DI + dbase + q];
        sxc[s][q] = xc[row*DI + dbase + q];
        sB[s][q]  = xd[row*56 + DTR + q];
        sC[s][q]  = xd[row*56 + DTR + DS + q];
        sz[s][q]  = zi[prow*DI + dbase + q];
    }
    __syncthreads();

    long idx = (((long)z*NCHUNK + chunk)*DI + d)*DS + n;
    float h = Hbuf[idx];
    for (int s = 0; s < CLEN; s++){
        float dtv = sdt[s][dg], xcv = sxc[s][dg];
        float dA = __expf(dtv*Aval);
        h = dA*h + (dtv*xcv)*sB[s][n];
        float contrib = h * sC[s][n];
        contrib += __shfl_xor(contrib, 8, 16);
        contrib += __shfl_xor(contrib, 4, 16);
        contrib += __shfl_xor(contrib, 2, 16);
        contrib += __shfl_xor(contrib, 1, 16);
        if (n == 0){
            int p = c0 + s;
            int phys = dir ? (L_SEQ-1-p) : p;
            long orow = (long)b*L_SEQ + phys;
            float zv = sz[s][dg];
            float sg = 1.f/(1.f + __expf(-zv));
            ys[orow*DI + d] = (contrib + Dval*xcv) * (zv*sg);
        }
    }
}

// ---------------- final rmsnorm: (res+h) normalized, f32 out ---------------------
__global__ __launch_bounds__(128) void rmsnorm_final_kernel(
        const float* __restrict__ res, const float* __restrict__ h,
        const float* __restrict__ w, float* __restrict__ out)
{
    int r = blockIdx.x; int tid = threadIdx.x;
    const float* hr = h + (long)r*DM;
    const float* rr = res + (long)r*DM;
    float v[3]; float ss = 0.f;
    #pragma unroll
    for (int i = 0; i < 3; i++){
        int c = tid + i*128;
        float x = rr[c] + hr[c];
        v[i] = x; ss += x*x;
    }
    #pragma unroll
    for (int off = 32; off; off >>= 1) ss += __shfl_down(ss, off, 64);
    __shared__ float wsum[2];
    if ((tid & 63) == 0) wsum[tid >> 6] = ss;
    __syncthreads();
    float scale = rsqrtf((wsum[0] + wsum[1]) / (float)DM + EPS_);
    #pragma unroll
    for (int i = 0; i < 3; i++){
        int c = tid + i*128;
        out[(long)r*DM + c] = v[i] * scale * w[c];
    }
}

extern "C" void kernel_launch(void* const* d_in, const int* in_sizes, int n_in,
                              void* d_out, int out_size, void* d_ws, size_t ws_size,
                              hipStream_t stream)
{
    const float* x         = (const float*)d_in[0];
    const float* patch_w   = (const float*)d_in[1];
    const float* patch_b   = (const float*)d_in[2];
    const float* pos_embed = (const float*)d_in[3];
    const float* temp_pos  = (const float*)d_in[4];
    const float* in_proj   = (const float*)d_in[5];
    const float* conv_w    = (const float*)d_in[6];
    const float* conv_b    = (const float*)d_in[7];
    const float* xproj_w   = (const float*)d_in[8];
    const float* dt_w      = (const float*)d_in[9];
    const float* dt_b      = (const float*)d_in[10];
    const float* A_log     = (const float*)d_in[11];
    const float* Dp        = (const float*)d_in[12];
    const float* conv_w_b  = (const float*)d_in[13];
    const float* conv_b_b  = (const float*)d_in[14];
    const float* xproj_w_b = (const float*)d_in[15];
    const float* dt_w_b    = (const float*)d_in[16];
    const float* dt_b_b    = (const float*)d_in[17];
    const float* A_log_b   = (const float*)d_in[18];
    const float* Dp_b      = (const float*)d_in[19];
    const float* out_proj  = (const float*)d_in[20];
    const float* norm_w    = (const float*)d_in[21];
    const float* norm_f    = (const float*)d_in[22];

    float* ws = (float*)d_ws;
    size_t off = 0;
    float* patches  = ws + off; off += (size_t)NROWS*768;      // 2,408,448
    float* hidden   = ws + off; off += (size_t)NROWS*DM;       // 1,204,224
    float* residual = ws + off; off += (size_t)NROWS*DM;
    float* hnorm    = ws + off; off += (size_t)NROWS*DM;       // dead after in_proj
    float* xi       = ws + off; off += (size_t)NROWS*DI;       // dead after conv
    float* ziB      = ws + off; off += (size_t)NROWS*DI;
    float* xc2      = ws + off; off += (size_t)2*NROWS*DI;
    float* xdbl2    = ws + off; off += (size_t)2*NROWS*56;
    float* dt2      = ws + off; off += (size_t)2*NROWS*DI;
    float* ysb      = ws + off; off += (size_t)NROWS*DI;
    float* ysf      = patches;            // alias: patches dead after patch GEMM
    // P/S buffers alias hnorm+xi (both dead by the time pass1 runs):
    // need 2 * 4*NCHUNK*DI*DS = 2*1,572,864 floats; hnorm+xi = 3,612,672 floats. fits.
    float* Pbuf = hnorm;                               // 1,572,864 floats
    float* Sbuf = hnorm + (size_t)4*NCHUNK*DI*DS;      // 1,572,864 floats (becomes Hin)

    hipMemsetAsync(residual, 0, (size_t)NROWS*DM*sizeof(float), stream);

    patchify_kernel<<<(NROWS*768+255)/256, 256, 0, stream>>>(x, patches);
    gemm_kernel<<<dim3(DM/64, NROWS/64), 256, 0, stream>>>(
        patches, nullptr, 768, patch_w, 768, DM, hidden, nullptr, 2,
        patch_b, pos_embed, temp_pos);

    for (int l = 0; l < DEPTH; l++){
        rmsnorm_kernel<<<NROWS, 128, 0, stream>>>(residual, hidden, hnorm,
                                                  norm_w + (size_t)l*DM);
        gemm_kernel<<<dim3(2*DI/64, NROWS/64), 256, 0, stream>>>(
            hnorm, nullptr, DM, in_proj + (size_t)l*2*DI*DM, DM, 2*DI,
            xi, ziB, 1, nullptr, nullptr, nullptr);
        conv_kernel<<<(2*NROWS*768+255)/256, 256, 0, stream>>>(
            xi, conv_w + (size_t)l*DI*KCONV, conv_b + (size_t)l*DI,
            conv_w_b + (size_t)l*DI*KCONV, conv_b_b + (size_t)l*DI, xc2);
        gemm_kernel<<<dim3(1, NROWS/64), 256, 0, stream>>>(
            xc2, nullptr, DI, xproj_w + (size_t)l*56*DI, DI, 56,
            xdbl2, nullptr, 0, nullptr, nullptr, nullptr);
        gemm_kernel<<<dim3(1, NROWS/64), 256, 0, stream>>>(
            xc2 + (size_t)NROWS*DI, nullptr, DI, xproj_w_b + (size_t)l*56*DI, DI, 56,
            xdbl2 + (size_t)NROWS*56, nullptr, 0, nullptr, nullptr, nullptr);
        gemm_kernel<<<dim3(DI/64, NROWS/64), 256, 0, stream>>>(
            xdbl2, nullptr, 56, dt_w + (size_t)l*DI*DTR, DTR, DI,
            dt2, nullptr, 3, dt_b + (size_t)l*DI, nullptr, nullptr);
        gemm_kernel<<<dim3(DI/64, NROWS/64), 256, 0, stream>>>(
            xdbl2 + (size_t)NROWS*56, nullptr, 56, dt_w_b + (size_t)l*DI*DTR, DTR, DI,
            dt2 + (size_t)NROWS*DI, nullptr, 3, dt_b_b + (size_t)l*DI, nullptr, nullptr);

        // chunked scan: pass1 -> combine -> pass2
        scan_pass1_kernel<<<dim3(DI/16, NCHUNK, 4), 256, 0, stream>>>(
            xc2, dt2, xdbl2, A_log + (size_t)l*DI*DS, A_log_b + (size_t)l*DI*DS,
            Pbuf, Sbuf);
        scan_combine_kernel<<<(4*DI*DS+255)/256, 256, 0, stream>>>(Pbuf, Sbuf);
        scan_pass2_kernel<<<dim3(DI/16, NCHUNK, 4), 256, 0, stream>>>(
            xc2, dt2, xdbl2, ziB,
            A_log + (size_t)l*DI*DS, Dp + (size_t)l*DI,
            A_log_b + (size_t)l*DI*DS, Dp_b + (size_t)l*DI,
            Sbuf, ysf, ysb);

        gemm_kernel<<<dim3(DM/64, NROWS/64), 256, 0, stream>>>(
            ysf, ysb, DI, out_proj + (size_t)l*DM*DI, DI, DM,
            hidden, nullptr, 0, nullptr, nullptr, nullptr);
    }

    rmsnorm_final_kernel<<<NROWS, 128, 0, stream>>>(residual, hidden,
                                                    norm_f, (float*)d_out);
}

// Round 4
// 6777.971 us; speedup vs baseline: 2.8327x; 1.4351x over previous
//
#include <hip/hip_runtime.h>
#include <hip/hip_bf16.h>

typedef unsigned short ushort_t;
typedef short bf16x8 __attribute__((ext_vector_type(8)));
typedef float f32x4  __attribute__((ext_vector_type(4)));

#define BATCH   2
#define FRAMES  8
#define GRID_   14
#define NTOK    196
#define PS      16
#define IMG     224
#define L_SEQ   1568
#define DM      384
#define DI      768
#define DTR     24
#define DS      16
#define DEPTH   24
#define KCONV   4
#define NROWS   (BATCH*L_SEQ)   // 3136
#define EPS_    1e-5f
#define NCHUNK  32
#define CLEN    49              // 32*49 = 1568

__device__ __forceinline__ ushort_t f2us(float f){
    __hip_bfloat16 h = __float2bfloat16(f);
    return *reinterpret_cast<ushort_t*>(&h);
}

// ---------------- patchify: x (B,3,T,224,224) f32 -> patches (3136,768) bf16 -----
__global__ __launch_bounds__(256) void patchify_kernel(const float* __restrict__ x,
                                                       ushort_t* __restrict__ patches){
    int idx = blockIdx.x*256 + threadIdx.x;
    if (idx >= NROWS*768) return;
    int k   = idx % 768;
    int r   = idx / 768;
    int tok = r % NTOK;
    int bt  = r / NTOK;
    int t = bt % FRAMES, b = bt / FRAMES;
    int gy = tok / GRID_, gx = tok % GRID_;
    int c = k / 256; int rem = k % 256; int py = rem/16, px = rem%16;
    long xo = (((long)(b*3 + c)*FRAMES + t)*IMG + (gy*PS+py))*IMG + (gx*PS+px);
    patches[idx] = f2us(x[xo]);
}

// ---------------- generic f32 -> bf16 convert ------------------------------------
__global__ __launch_bounds__(256) void convert_kernel(const float* __restrict__ in,
                                                      ushort_t* __restrict__ out, int n){
    int i = blockIdx.x*256 + threadIdx.x;
    if (i < n) out[i] = f2us(in[i]);
}

// ---------------- per-layer weight conversion (wi|wo|wxf|wxb|wdtf|wdtb) ----------
#define WI_SZ  (2*DI*DM)      // 589824
#define WO_SZ  (DM*DI)        // 294912
#define WX_SZ  (56*DI)        // 43008
#define WDT_SZ (DI*32)        // 24576 (padded K 24->32)
#define WCVT_TOTAL (WI_SZ + WO_SZ + 2*WX_SZ + 2*WDT_SZ)   // 1,019,904

__global__ __launch_bounds__(256) void convert_layer_kernel(
        const float* __restrict__ wi, const float* __restrict__ wo,
        const float* __restrict__ wxf, const float* __restrict__ wxb,
        const float* __restrict__ wdtf, const float* __restrict__ wdtb,
        ushort_t* __restrict__ out)
{
    int gid = blockIdx.x*256 + threadIdx.x;
    if (gid >= WCVT_TOTAL) return;
    float v;
    if (gid < WI_SZ)                       v = wi[gid];
    else if (gid < WI_SZ+WO_SZ)            v = wo[gid - WI_SZ];
    else if (gid < WI_SZ+WO_SZ+WX_SZ)      v = wxf[gid - WI_SZ - WO_SZ];
    else if (gid < WI_SZ+WO_SZ+2*WX_SZ)    v = wxb[gid - WI_SZ - WO_SZ - WX_SZ];
    else if (gid < WI_SZ+WO_SZ+2*WX_SZ+WDT_SZ){
        int i = gid - (WI_SZ+WO_SZ+2*WX_SZ);
        int rr = i >> 5, c = i & 31;
        v = (c < DTR) ? wdtf[rr*DTR + c] : 0.f;
    } else {
        int i = gid - (WI_SZ+WO_SZ+2*WX_SZ+WDT_SZ);
        int rr = i >> 5, c = i & 31;
        v = (c < DTR) ? wdtb[rr*DTR + c] : 0.f;
    }
    out[gid] = f2us(v);
}

// ---------------- MFMA GEMM: C[M,N] = A[M,K] * W[N,K]^T, bf16 in, f32 out --------
// grid (N/64, M/64, Z); block 256 = 4 waves; wave computes 64(m) x 16(n).
// modes: 0 plain; 1 in_proj split; 2 patch epilogue(+aux); 3 dt softplus(+bias z-sel);
//        4 xproj (f32 cn<56 -> out0, bf16 cn<32 -> outb with 24..31 zeroed)
__global__ __launch_bounds__(256) void gemm_mfma_kernel(
        const ushort_t* __restrict__ A, int lda, long strideA,
        const ushort_t* __restrict__ W, int ldw, long strideW,
        int K, int N,
        float* __restrict__ out0, long strideO0,
        float* __restrict__ out1, ushort_t* __restrict__ outb, long strideOb,
        int mode,
        const float* __restrict__ aux0, const float* __restrict__ aux1,
        const float* __restrict__ aux2)
{
    int z = blockIdx.z;
    A    += (long)z * strideA;
    W    += (long)z * strideW;
    out0 += (long)z * strideO0;
    if (outb) outb += (long)z * strideOb;

    int tid  = threadIdx.x;
    int wave = tid >> 6, lane = tid & 63;
    int l15 = lane & 15, quad = lane >> 4;
    int m0 = blockIdx.y * 64, n0 = blockIdx.x * 64;

    const ushort_t* wp = W + (long)(n0 + wave*16 + l15)*ldw + quad*8;
    const ushort_t* ap0 = A + (long)(m0 + l15)*lda + quad*8;

    f32x4 acc[4] = {f32x4{0,0,0,0}, f32x4{0,0,0,0}, f32x4{0,0,0,0}, f32x4{0,0,0,0}};

    for (int k0 = 0; k0 < K; k0 += 32){
        bf16x8 bfrag = *reinterpret_cast<const bf16x8*>(wp + k0);
        #pragma unroll
        for (int mt = 0; mt < 4; mt++){
            bf16x8 afrag = *reinterpret_cast<const bf16x8*>(ap0 + (long)mt*16*lda + k0);
            acc[mt] = __builtin_amdgcn_mfma_f32_16x16x32_bf16(afrag, bfrag, acc[mt], 0, 0, 0);
        }
    }

    int cn = n0 + wave*16 + l15;
    #pragma unroll
    for (int mt = 0; mt < 4; mt++){
        #pragma unroll
        for (int r = 0; r < 4; r++){
            int row = m0 + mt*16 + quad*4 + r;
            float v = acc[mt][r];
            if (mode == 0){
                out0[(long)row*N + cn] = v;
            } else if (mode == 1){
                if (cn < DI) out0[(long)row*DI + cn] = v;
                else         out1[(long)row*DI + cn - DI] = v;
            } else if (mode == 2){
                int tok = row % NTOK, t = (row/NTOK) % FRAMES;
                out0[(long)row*N + cn] = v + aux0[cn] + aux1[tok*DM+cn] + aux2[t*DM+cn];
            } else if (mode == 3){
                const float* bias = z ? aux1 : aux0;
                float xs = v + bias[cn];
                out0[(long)row*N + cn] = (xs > 20.f) ? xs : log1pf(__expf(xs));
            } else { // mode 4: xproj
                if (cn < 56) out0[(long)row*56 + cn] = v;
                if (cn < 32) outb[(long)row*32 + cn] = f2us(cn < DTR ? v : 0.f);
            }
        }
    }
}

// ---------------- rmsnorm (+ residual add), bf16 out -----------------------------
__global__ __launch_bounds__(128) void rmsnorm_kernel(
        float* __restrict__ res, const float* __restrict__ h,
        ushort_t* __restrict__ outb, const float* __restrict__ w)
{
    int r = blockIdx.x; int tid = threadIdx.x;
    const float* hr = h + (long)r*DM;
    float* rr = res + (long)r*DM;
    float v[3]; float ss = 0.f;
    #pragma unroll
    for (int i = 0; i < 3; i++){
        int c = tid + i*128;
        float x = rr[c] + hr[c];
        rr[c] = x; v[i] = x; ss += x*x;
    }
    #pragma unroll
    for (int off = 32; off; off >>= 1) ss += __shfl_down(ss, off, 64);
    __shared__ float wsum[2];
    if ((tid & 63) == 0) wsum[tid >> 6] = ss;
    __syncthreads();
    float scale = rsqrtf((wsum[0] + wsum[1]) / (float)DM + EPS_);
    #pragma unroll
    for (int i = 0; i < 3; i++){
        int c = tid + i*128;
        outb[(long)r*DM + c] = f2us(v[i] * scale * w[c]);
    }
}

// ---------------- depthwise causal conv + silu, f32 + bf16 out -------------------
__global__ __launch_bounds__(256) void conv_kernel(
        const float* __restrict__ xi,
        const float* __restrict__ cw_f, const float* __restrict__ cb_f,
        const float* __restrict__ cw_b, const float* __restrict__ cb_b,
        float* __restrict__ xc, ushort_t* __restrict__ xcb)
{
    int idx = blockIdx.x*256 + threadIdx.x;
    if (idx >= 2*NROWS*768) return;
    int d  = idx % 768;
    int r2 = idx / 768;
    int dir = r2 / NROWS;
    int rr  = r2 % NROWS;
    int b = rr / L_SEQ, p = rr % L_SEQ;
    const float* cw = dir ? cw_b : cw_f;
    const float* cb = dir ? cb_b : cb_f;
    float acc = cb[d];
    #pragma unroll
    for (int j = 0; j < KCONV; j++){
        int pp = p - (KCONV-1) + j;
        if (pp >= 0){
            int phys = dir ? (L_SEQ-1-pp) : pp;
            acc += cw[d*KCONV+j] * xi[((long)b*L_SEQ + phys)*DI + d];
        }
    }
    float sg = 1.f/(1.f + __expf(-acc));
    float val = acc * sg;
    xc[idx]  = val;
    xcb[idx] = f2us(val);
}

// ---------------- chunked selective scan -----------------------------------------
__global__ __launch_bounds__(256) void scan_pass1_kernel(
        const float* __restrict__ xc2, const float* __restrict__ dt2,
        const float* __restrict__ xdbl2,
        const float* __restrict__ Alog_f, const float* __restrict__ Alog_b,
        float* __restrict__ Pbuf, float* __restrict__ Sbuf)
{
    int dchunk = blockIdx.x;
    int chunk  = blockIdx.y;
    int z      = blockIdx.z;
    int b = z & 1, dir = z >> 1;
    int tid = threadIdx.x;
    int n = tid & 15, dg = tid >> 4;
    int dbase = dchunk*16;
    int d = dbase + dg;

    const float* xc = xc2 + (long)dir*NROWS*DI;
    const float* dt = dt2 + (long)dir*NROWS*DI;
    const float* xd = xdbl2 + (long)dir*NROWS*56;
    const float* Alog = dir ? Alog_b : Alog_f;
    float Aval = -__expf(Alog[d*DS + n]);

    __shared__ float sdt[CLEN][16], sxc[CLEN][16], sB[CLEN][16];
    int c0 = chunk * CLEN;
    for (int e = tid; e < CLEN*16; e += 256){
        int s = e >> 4, q = e & 15;
        long row = (long)b*L_SEQ + c0 + s;
        sdt[s][q] = dt[row*DI + dbase + q];
        sxc[s][q] = xc[row*DI + dbase + q];
        sB[s][q]  = xd[row*56 + DTR + q];
    }
    __syncthreads();

    float h = 0.f, dts = 0.f;
    for (int s = 0; s < CLEN; s++){
        float dtv = sdt[s][dg], xcv = sxc[s][dg];
        dts += dtv;
        h = __expf(dtv*Aval)*h + (dtv*xcv)*sB[s][n];
    }
    long idx = (((long)z*NCHUNK + chunk)*DI + d)*DS + n;
    Pbuf[idx] = __expf(Aval*dts);
    Sbuf[idx] = h;
}

__global__ __launch_bounds__(256) void scan_combine_kernel(
        const float* __restrict__ Pbuf, float* __restrict__ Sbuf)
{
    int gid = blockIdx.x*256 + threadIdx.x;
    if (gid >= 4*DI*DS) return;
    int dn = gid % (DI*DS);
    int z  = gid / (DI*DS);
    long idx = (long)z*NCHUNK*DI*DS + dn;
    float Pv = Pbuf[idx], Sv = Sbuf[idx];
    float hin = 0.f;
    for (int c = 0; c < NCHUNK; c++){
        float Pn = 0.f, Sn = 0.f;
        if (c+1 < NCHUNK){ Pn = Pbuf[idx + DI*DS]; Sn = Sbuf[idx + DI*DS]; }
        Sbuf[idx] = hin;
        hin = Pv*hin + Sv;
        Pv = Pn; Sv = Sn;
        idx += DI*DS;
    }
}

__global__ __launch_bounds__(256) void scan_pass2_kernel(
        const float* __restrict__ xc2, const float* __restrict__ dt2,
        const float* __restrict__ xdbl2, const float* __restrict__ zi,
        const float* __restrict__ Alog_f, const float* __restrict__ Dp_f,
        const float* __restrict__ Alog_b, const float* __restrict__ Dp_b,
        const float* __restrict__ Hbuf,
        float* __restrict__ ys_f, float* __restrict__ ys_b)
{
    int dchunk = blockIdx.x;
    int chunk  = blockIdx.y;
    int z      = blockIdx.z;
    int b = z & 1, dir = z >> 1;
    int tid = threadIdx.x;
    int n = tid & 15, dg = tid >> 4;
    int dbase = dchunk*16;
    int d = dbase + dg;

    const float* xc = xc2 + (long)dir*NROWS*DI;
    const float* dt = dt2 + (long)dir*NROWS*DI;
    const float* xd = xdbl2 + (long)dir*NROWS*56;
    const float* Alog = dir ? Alog_b : Alog_f;
    const float* Dpp  = dir ? Dp_b   : Dp_f;
    float* ys = dir ? ys_b : ys_f;

    float Aval = -__expf(Alog[d*DS + n]);
    float Dval = Dpp[d];

    __shared__ float sdt[CLEN][16], sxc[CLEN][16], sB[CLEN][16], sC[CLEN][16], sz[CLEN][16];
    int c0 = chunk * CLEN;
    for (int e = tid; e < CLEN*16; e += 256){
        int s = e >> 4, q = e & 15;
        int p = c0 + s;
        int phys = dir ? (L_SEQ-1-p) : p;
        long row  = (long)b*L_SEQ + p;
        long prow = (long)b*L_SEQ + phys;
        sdt[s][q] = dt[row*DI + dbase + q];
        sxc[s][q] = xc[row*DI + dbase + q];
        sB[s][q]  = xd[row*56 + DTR + q];
        sC[s][q]  = xd[row*56 + DTR + DS + q];
        sz[s][q]  = zi[prow*DI + dbase + q];
    }
    __syncthreads();

    long idx = (((long)z*NCHUNK + chunk)*DI + d)*DS + n;
    float h = Hbuf[idx];
    for (int s = 0; s < CLEN; s++){
        float dtv = sdt[s][dg], xcv = sxc[s][dg];
        float dA = __expf(dtv*Aval);
        h = dA*h + (dtv*xcv)*sB[s][n];
        float contrib = h * sC[s][n];
        contrib += __shfl_xor(contrib, 8, 16);
        contrib += __shfl_xor(contrib, 4, 16);
        contrib += __shfl_xor(contrib, 2, 16);
        contrib += __shfl_xor(contrib, 1, 16);
        if (n == 0){
            int p = c0 + s;
            int phys = dir ? (L_SEQ-1-p) : p;
            long orow = (long)b*L_SEQ + phys;
            float zv = sz[s][dg];
            float sg = 1.f/(1.f + __expf(-zv));
            ys[orow*DI + d] = (contrib + Dval*xcv) * (zv*sg);
        }
    }
}

// ---------------- ys add + bf16 convert ------------------------------------------
__global__ __launch_bounds__(256) void ys_add_kernel(
        const float* __restrict__ ysf, const float* __restrict__ ysb,
        ushort_t* __restrict__ out)
{
    int i = blockIdx.x*256 + threadIdx.x;
    if (i < NROWS*DI) out[i] = f2us(ysf[i] + ysb[i]);
}

// ---------------- final rmsnorm --------------------------------------------------
__global__ __launch_bounds__(128) void rmsnorm_final_kernel(
        const float* __restrict__ res, const float* __restrict__ h,
        const float* __restrict__ w, float* __restrict__ out)
{
    int r = blockIdx.x; int tid = threadIdx.x;
    const float* hr = h + (long)r*DM;
    const float* rr = res + (long)r*DM;
    float v[3]; float ss = 0.f;
    #pragma unroll
    for (int i = 0; i < 3; i++){
        int c = tid + i*128;
        float x = rr[c] + hr[c];
        v[i] = x; ss += x*x;
    }
    #pragma unroll
    for (int off = 32; off; off >>= 1) ss += __shfl_down(ss, off, 64);
    __shared__ float wsum[2];
    if ((tid & 63) == 0) wsum[tid >> 6] = ss;
    __syncthreads();
    float scale = rsqrtf((wsum[0] + wsum[1]) / (float)DM + EPS_);
    #pragma unroll
    for (int i = 0; i < 3; i++){
        int c = tid + i*128;
        out[(long)r*DM + c] = v[i] * scale * w[c];
    }
}

extern "C" void kernel_launch(void* const* d_in, const int* in_sizes, int n_in,
                              void* d_out, int out_size, void* d_ws, size_t ws_size,
                              hipStream_t stream)
{
    const float* x         = (const float*)d_in[0];
    const float* patch_w   = (const float*)d_in[1];
    const float* patch_b   = (const float*)d_in[2];
    const float* pos_embed = (const float*)d_in[3];
    const float* temp_pos  = (const float*)d_in[4];
    const float* in_proj   = (const float*)d_in[5];
    const float* conv_w    = (const float*)d_in[6];
    const float* conv_b    = (const float*)d_in[7];
    const float* xproj_w   = (const float*)d_in[8];
    const float* dt_w      = (const float*)d_in[9];
    const float* dt_b      = (const float*)d_in[10];
    const float* A_log     = (const float*)d_in[11];
    const float* Dp        = (const float*)d_in[12];
    const float* conv_w_b  = (const float*)d_in[13];
    const float* conv_b_b  = (const float*)d_in[14];
    const float* xproj_w_b = (const float*)d_in[15];
    const float* dt_w_b    = (const float*)d_in[16];
    const float* dt_b_b    = (const float*)d_in[17];
    const float* A_log_b   = (const float*)d_in[18];
    const float* Dp_b      = (const float*)d_in[19];
    const float* out_proj  = (const float*)d_in[20];
    const float* norm_w    = (const float*)d_in[21];
    const float* norm_f    = (const float*)d_in[22];

    float* ws = (float*)d_ws;
    size_t off = 0;
    float* ysf      = ws + off; off += (size_t)NROWS*DI;       // 2,408,448
    float* hidden   = ws + off; off += (size_t)NROWS*DM;
    float* residual = ws + off; off += (size_t)NROWS*DM;
    float* hnormreg = ws + off; off += (size_t)NROWS*DM;       // hnorm_bf, later Pbuf start
    float* xi       = ws + off; off += (size_t)NROWS*DI;       // patches_bf pre-loop; Sbuf tail
    float* ziB      = ws + off; off += (size_t)NROWS*DI;
    float* xc2      = ws + off; off += (size_t)2*NROWS*DI;
    float* xdbl2    = ws + off; off += (size_t)2*NROWS*56;
    float* dt2      = ws + off; off += (size_t)2*NROWS*DI;     // ys_bf aliased after pass2
    float* ysb      = ws + off; off += (size_t)NROWS*DI;       // xc2_bf aliased (dead before pass2)
    float* xdblbf_f = ws + off; off += (size_t)2*NROWS*32/2;   // 100,352 floats
    float* wbf_f    = ws + off; off += (size_t)(WCVT_TOTAL+1)/2;   // per-layer bf16 weights
    float* wpbf_f   = ws + off; off += (size_t)(DM*DI+1)/2;

    ushort_t* hnorm_bf   = (ushort_t*)hnormreg;
    ushort_t* patches_bf = (ushort_t*)xi;
    ushort_t* xc2_bf     = (ushort_t*)ysb;
    ushort_t* xdbl_bf    = (ushort_t*)xdblbf_f;
    ushort_t* ys_bf      = (ushort_t*)dt2;
    ushort_t* wbf        = (ushort_t*)wbf_f;
    ushort_t* wp_bf      = (ushort_t*)wpbf_f;
    ushort_t* wi_bf  = wbf;
    ushort_t* wo_bf  = wbf + WI_SZ;
    ushort_t* wx_bf  = wbf + WI_SZ + WO_SZ;           // [2][WX_SZ]
    ushort_t* wdt_bf = wbf + WI_SZ + WO_SZ + 2*WX_SZ; // [2][WDT_SZ]
    float* Pbuf = hnormreg;                            // 1,572,864 floats
    float* Sbuf = hnormreg + (size_t)4*NCHUNK*DI*DS;   // spills into xi region

    hipMemsetAsync(residual, 0, (size_t)NROWS*DM*sizeof(float), stream);

    patchify_kernel<<<(NROWS*768+255)/256, 256, 0, stream>>>(x, patches_bf);
    convert_kernel<<<(DM*DI+255)/256, 256, 0, stream>>>(patch_w, wp_bf, DM*DI);
    // patch embed: patches_bf x wp_bf -> hidden (+bias+pos+temp)
    gemm_mfma_kernel<<<dim3(DM/64, NROWS/64, 1), 256, 0, stream>>>(
        patches_bf, DI, 0, wp_bf, DI, 0, DI, DM,
        hidden, 0, nullptr, nullptr, 0, 2, patch_b, pos_embed, temp_pos);

    for (int l = 0; l < DEPTH; l++){
        convert_layer_kernel<<<(WCVT_TOTAL+255)/256, 256, 0, stream>>>(
            in_proj + (size_t)l*WI_SZ, out_proj + (size_t)l*WO_SZ,
            xproj_w + (size_t)l*WX_SZ, xproj_w_b + (size_t)l*WX_SZ,
            dt_w + (size_t)l*DI*DTR, dt_w_b + (size_t)l*DI*DTR, wbf);

        rmsnorm_kernel<<<NROWS, 128, 0, stream>>>(residual, hidden, hnorm_bf,
                                                  norm_w + (size_t)l*DM);
        // in_proj: hnorm_bf(3136,384) x wi(1536,384)^T -> xi, ziB
        gemm_mfma_kernel<<<dim3(2*DI/64, NROWS/64, 1), 256, 0, stream>>>(
            hnorm_bf, DM, 0, wi_bf, DM, 0, DM, 2*DI,
            xi, 0, ziB, nullptr, 0, 1, nullptr, nullptr, nullptr);

        conv_kernel<<<(2*NROWS*768+255)/256, 256, 0, stream>>>(
            xi, conv_w + (size_t)l*DI*KCONV, conv_b + (size_t)l*DI,
            conv_w_b + (size_t)l*DI*KCONV, conv_b_b + (size_t)l*DI, xc2, xc2_bf);

        // xproj fwd+bwd: xc2_bf x wx^T -> xdbl2 (f32) + xdbl_bf (bf16, K-padded)
        gemm_mfma_kernel<<<dim3(1, NROWS/64, 2), 256, 0, stream>>>(
            xc2_bf, DI, (long)NROWS*DI, wx_bf, DI, WX_SZ, DI, 64,
            xdbl2, (long)NROWS*56, nullptr, xdbl_bf, (long)NROWS*32, 4,
            nullptr, nullptr, nullptr);

        // dt fwd+bwd: xdbl_bf(3136,32) x wdt(768,32)^T + bias, softplus -> dt2
        gemm_mfma_kernel<<<dim3(DI/64, NROWS/64, 2), 256, 0, stream>>>(
            xdbl_bf, 32, (long)NROWS*32, wdt_bf, 32, WDT_SZ, 32, DI,
            dt2, (long)NROWS*DI, nullptr, nullptr, 0, 3,
            dt_b + (size_t)l*DI, dt_b_b + (size_t)l*DI, nullptr);

        scan_pass1_kernel<<<dim3(DI/16, NCHUNK, 4), 256, 0, stream>>>(
            xc2, dt2, xdbl2, A_log + (size_t)l*DI*DS, A_log_b + (size_t)l*DI*DS,
            Pbuf, Sbuf);
        scan_combine_kernel<<<(4*DI*DS+255)/256, 256, 0, stream>>>(Pbuf, Sbuf);
        scan_pass2_kernel<<<dim3(DI/16, NCHUNK, 4), 256, 0, stream>>>(
            xc2, dt2, xdbl2, ziB,
            A_log + (size_t)l*DI*DS, Dp + (size_t)l*DI,
            A_log_b + (size_t)l*DI*DS, Dp_b + (size_t)l*DI,
            Sbuf, ysf, ysb);

        ys_add_kernel<<<(NROWS*DI+255)/256, 256, 0, stream>>>(ysf, ysb, ys_bf);

        // out_proj: ys_bf(3136,768) x wo(384,768)^T -> hidden
        gemm_mfma_kernel<<<dim3(DM/64, NROWS/64, 1), 256, 0, stream>>>(
            ys_bf, DI, 0, wo_bf, DI, 0, DI, DM,
            hidden, 0, nullptr, nullptr, 0, 0, nullptr, nullptr, nullptr);
    }

    rmsnorm_final_kernel<<<NROWS, 128, 0, stream>>>(residual, hidden,
                                                    norm_f, (float*)d_out);
}